// Round 1
// baseline (88.154 us; speedup 1.0000x reference)
//
#include <hip/hip_runtime.h>

#define HDIM 512
#define NH   32
#define LTOT 8192
#define LBLK 2048   // l-range per block (L / 4)
#define CHUNK 8     // consecutive l per thread
#define TPB  256

// One block = one (h, l-quarter). Threads 0..31 compute the per-(h,n) params
// into LDS (recomputed per block -- trivial cost, avoids d_ws dependency and a
// second launch). Then each thread evaluates CHUNK consecutive l via an exact
// transcendental start + complex-multiply recurrence K <- K*w.
__global__ __launch_bounds__(TPB, 4) void s4_kernel(
    const float* __restrict__ log_dt,
    const float* __restrict__ log_A_real,
    const float* __restrict__ A_imag,
    const float* __restrict__ Bmat,
    const float* __restrict__ Cmat,
    float* __restrict__ out)
{
    __shared__ float4 p0[NH]; // re, im, wr, wi
    __shared__ float2 p1[NH]; // 2*Ceff_r, 2*Ceff_i

    const int bid = blockIdx.x;
    const int h   = bid >> 2;       // 512 h
    const int q   = bid & 3;        // 4 l-quarters
    const int tid = threadIdx.x;

    if (tid < NH) {
        const int n   = tid;
        const int idx = h * NH + n;
        const float dt = __expf(log_dt[h]);
        const float Ar = -__expf(log_A_real[idx]);   // A = -exp(lar) - i*A_imag
        const float Ai = -A_imag[idx];
        const float re = Ar * dt;                    // dtA
        const float im = Ai * dt;
        float s, c;
        __sincosf(im, &s, &c);
        const float e  = __expf(re);
        const float wr = e * c;                      // w = exp(dtA)
        const float wi = e * s;
        // (w - 1) / A
        const float inv = 1.0f / (Ar * Ar + Ai * Ai);
        const float nr = wr - 1.0f, ni = wi;
        const float qr = (nr * Ar + ni * Ai) * inv;
        const float qi = (ni * Ar - nr * Ai) * inv;
        // Bc * Cc
        const float Br = Bmat[2 * idx], Bi = Bmat[2 * idx + 1];
        const float Cr = Cmat[2 * idx], Ci = Cmat[2 * idx + 1];
        const float bcr = Br * Cr - Bi * Ci;
        const float bci = Br * Ci + Bi * Cr;
        // 2 * Ceff
        const float c2r = 2.0f * (bcr * qr - bci * qi);
        const float c2i = 2.0f * (bcr * qi + bci * qr);
        p0[n] = make_float4(re, im, wr, wi);
        p1[n] = make_float2(c2r, c2i);
    }
    __syncthreads();

    const int   l0  = q * LBLK + tid * CHUNK;
    const float l0f = (float)l0;

    float acc[CHUNK];
#pragma unroll
    for (int j = 0; j < CHUNK; ++j) acc[j] = 0.0f;

#pragma unroll 1
    for (int n = 0; n < NH; ++n) {
        const float4 P  = p0[n];
        const float  ax = P.x * l0f;          // re * l0  (<= 0)
        if (ax < -30.0f) continue;            // e^-30 ~ 1e-13: negligible, only decays
        const float2 Q = p1[n];
        float s, c;
        __sincosf(P.y * l0f, &s, &c);
        const float e0 = __expf(ax);
        float kr = e0 * c;                    // K(l0) = exp(dtA*l0)
        float ki = e0 * s;
#pragma unroll
        for (int j = 0; j < CHUNK; ++j) {
            acc[j] = fmaf(Q.x, kr, fmaf(-Q.y, ki, acc[j]));  // += 2Re(Ceff*K)
            const float t = fmaf(kr, P.z, -(ki * P.w));      // K *= w
            ki = fmaf(kr, P.w, ki * P.z);
            kr = t;
        }
    }

    float4* o = (float4*)(out + (size_t)h * LTOT + l0);
    o[0] = make_float4(acc[0], acc[1], acc[2], acc[3]);
    o[1] = make_float4(acc[4], acc[5], acc[6], acc[7]);
}

extern "C" void kernel_launch(void* const* d_in, const int* in_sizes, int n_in,
                              void* d_out, int out_size, void* d_ws, size_t ws_size,
                              hipStream_t stream)
{
    (void)in_sizes; (void)n_in; (void)d_ws; (void)ws_size; (void)out_size;
    const float* log_dt     = (const float*)d_in[0];
    const float* log_A_real = (const float*)d_in[1];
    const float* A_imag     = (const float*)d_in[2];
    const float* Bmat       = (const float*)d_in[3];
    const float* Cmat       = (const float*)d_in[4];
    float* out = (float*)d_out;

    s4_kernel<<<dim3(HDIM * (LTOT / LBLK)), dim3(TPB), 0, stream>>>(
        log_dt, log_A_real, A_imag, Bmat, Cmat, out);
}

// Round 2
// 81.560 us; speedup vs baseline: 1.0808x; 1.0808x over previous
//
#include <hip/hip_runtime.h>
#include <math.h>

#define HDIM 512
#define NH   32
#define LTOT 8192
#define HALF 4096   // l-range per block
#define CHUNK 16    // consecutive l per thread
#define TPB  256

// One block = one (h, l-half). Threads 0..31 compute per-(h,n) params into LDS.
// Each thread evaluates CHUNK consecutive l of out[h, :] via an exact start
// (raw v_sin/v_cos/v_exp on precomputed revolution/log2 scales) plus the real
// two-term recurrence u_{j+1} = a*u_j - b*u_{j-1}, a=2Re(w), b=|w|^2=e^{2re}.
// 3 VALU ops per (n,l) element vs 6 for the complex recurrence.
__global__ __launch_bounds__(TPB, 4) void s4_kernel(
    const float* __restrict__ log_dt,
    const float* __restrict__ log_A_real,
    const float* __restrict__ A_imag,
    const float* __restrict__ Bmat,
    const float* __restrict__ Cmat,
    float* __restrict__ out)
{
    __shared__ float4 p0[NH]; // re*log2e, im/(2pi), a=2wr, b=e^{2re}
    __shared__ float4 p1[NH]; // c2r, c2i, dr, di   (c2=2*Ceff, D=2*Ceff*w)

    const int bid  = blockIdx.x;
    const int h    = bid >> 1;
    const int half = bid & 1;
    const int tid  = threadIdx.x;

    if (tid < NH) {
        const int n   = tid;
        const int idx = h * NH + n;
        const float dt = expf(log_dt[h]);
        const float Ar = -expf(log_A_real[idx]);   // A = -exp(lar) - i*A_imag
        const float Ai = -A_imag[idx];
        const float re = Ar * dt;                  // dtA (re < 0)
        const float im = Ai * dt;
        float sw, cw;
        sincosf(im, &sw, &cw);                     // precise: small arg
        const float er = expf(re);
        const float wr = er * cw;                  // w = exp(dtA)
        const float wi = er * sw;
        // (w - 1) / A
        const float inv = 1.0f / (Ar * Ar + Ai * Ai);
        const float nr = wr - 1.0f, ni = wi;
        const float qr = (nr * Ar + ni * Ai) * inv;
        const float qi = (ni * Ar - nr * Ai) * inv;
        // 2 * Bc * Cc * (w-1)/A
        const float Br = Bmat[2 * idx], Bi = Bmat[2 * idx + 1];
        const float Cr = Cmat[2 * idx], Ci = Cmat[2 * idx + 1];
        const float bcr = Br * Cr - Bi * Ci;
        const float bci = Br * Ci + Bi * Cr;
        const float c2r = 2.0f * (bcr * qr - bci * qi);
        const float c2i = 2.0f * (bcr * qi + bci * qr);
        // D = c2 * w  (for the u(l0+1) start)
        const float dr = c2r * wr - c2i * wi;
        const float di = c2r * wi + c2i * wr;
        p0[n] = make_float4(re * 1.44269504089f, im * 0.15915494309f,
                            2.0f * wr, er * er);
        p1[n] = make_float4(c2r, c2i, dr, di);
    }
    __syncthreads();

    const int   l0  = half * HALF + tid * CHUNK;
    const float l0f = (float)l0;

    float acc[CHUNK];
#pragma unroll
    for (int j = 0; j < CHUNK; ++j) acc[j] = 0.0f;

#pragma unroll 1
    for (int n = 0; n < NH; ++n) {
        const float4 P0 = p0[n];
        const float ax2 = P0.x * l0f;          // re*log2e*l0  (<= 0)
        if (ax2 < -43.3f) continue;            // 2^-43.3 ~ 1e-13: negligible
        const float4 P1 = p1[n];
        float ph = P0.y * l0f;                 // phase in revolutions
        ph -= floorf(ph);
        const float s = __builtin_amdgcn_sinf(ph);   // sin(2*pi*ph)
        const float c = __builtin_amdgcn_cosf(ph);
        const float e = __builtin_amdgcn_exp2f(ax2); // e^{re*l0}
        const float kr = e * c;                // K(l0) = exp(dtA*l0)
        const float ki = e * s;
        float u0 = fmaf(P1.x, kr, -(P1.y * ki));   // u(l0)   = 2Re(c*K)
        float u1 = fmaf(P1.z, kr, -(P1.w * ki));   // u(l0+1) = 2Re(c*w*K)
        acc[0] += u0;
        acc[1] += u1;
#pragma unroll
        for (int j = 2; j < CHUNK; ++j) {
            const float un = fmaf(P0.z, u1, -(P0.w * u0));  // a*u1 - b*u0
            acc[j] += un;
            u0 = u1;
            u1 = un;
        }
    }

    float4* o = (float4*)(out + (size_t)h * LTOT + l0);
#pragma unroll
    for (int j = 0; j < CHUNK / 4; ++j)
        o[j] = make_float4(acc[4 * j], acc[4 * j + 1], acc[4 * j + 2], acc[4 * j + 3]);
}

extern "C" void kernel_launch(void* const* d_in, const int* in_sizes, int n_in,
                              void* d_out, int out_size, void* d_ws, size_t ws_size,
                              hipStream_t stream)
{
    (void)in_sizes; (void)n_in; (void)d_ws; (void)ws_size; (void)out_size;
    const float* log_dt     = (const float*)d_in[0];
    const float* log_A_real = (const float*)d_in[1];
    const float* A_imag     = (const float*)d_in[2];
    const float* Bmat       = (const float*)d_in[3];
    const float* Cmat       = (const float*)d_in[4];
    float* out = (float*)d_out;

    s4_kernel<<<dim3(HDIM * (LTOT / HALF)), dim3(TPB), 0, stream>>>(
        log_dt, log_A_real, A_imag, Bmat, Cmat, out);
}

// Round 3
// 78.658 us; speedup vs baseline: 1.1207x; 1.0369x over previous
//
#include <hip/hip_runtime.h>
#include <math.h>

#define HDIM 512
#define NH   32
#define LTOT 8192
#define HALF 4096   // l-range per block
#define CHUNK 16    // consecutive l per thread (8 packed pairs)
#define TPB  256

typedef float v2f __attribute__((ext_vector_type(2)));

// One block = one (h, l-half). Threads 0..31 compute per-(h,n) params into LDS.
// Each thread evaluates CHUNK consecutive l via an exact transcendental start
// plus a PACKED stride-2 real recurrence: with u_j = 2Re(Ceff w^j K(l0)),
// the pairs P_k = (u_{2k}, u_{2k+1}) satisfy P_{k+1} = a2*P_k - b2*P_{k-1}
// elementwise, a2 = 2Re(w^2), b2 = |w|^4 (roots w^2, conj -- |.|<1, stable).
// Targets v_pk_mul_f32/v_pk_fma_f32: 3 packed ops per 2 elements.
__global__ __launch_bounds__(TPB, 4) void s4_kernel(
    const float* __restrict__ log_dt,
    const float* __restrict__ log_A_real,
    const float* __restrict__ A_imag,
    const float* __restrict__ Bmat,
    const float* __restrict__ Cmat,
    float* __restrict__ out)
{
    __shared__ float4 p0[NH]; // re*log2e, im/(2pi), a2=2Re(w^2), b2=|w|^4
    __shared__ float4 p1[NH]; // E0r, E1r, E0i, E1i   (Ej = 2*Ceff*w^j)
    __shared__ float4 p2[NH]; // E2r, E3r, E2i, E3i

    const int bid  = blockIdx.x;
    const int h    = bid >> 1;
    const int half = bid & 1;
    const int tid  = threadIdx.x;

    if (tid < NH) {
        const int n   = tid;
        const int idx = h * NH + n;
        const float dt = expf(log_dt[h]);
        const float Ar = -expf(log_A_real[idx]);   // A = -exp(lar) - i*A_imag
        const float Ai = -A_imag[idx];
        const float re = Ar * dt;                  // dtA (re < 0)
        const float im = Ai * dt;
        float sw, cw;
        sincosf(im, &sw, &cw);                     // precise: small arg
        const float er = expf(re);
        const float wr = er * cw;                  // w = exp(dtA)
        const float wi = er * sw;
        // (w - 1) / A
        const float inv = 1.0f / (Ar * Ar + Ai * Ai);
        const float nr = wr - 1.0f, ni = wi;
        const float qr = (nr * Ar + ni * Ai) * inv;
        const float qi = (ni * Ar - nr * Ai) * inv;
        // E0 = 2 * Bc * Cc * (w-1)/A
        const float Br = Bmat[2 * idx], Bi = Bmat[2 * idx + 1];
        const float Cr = Cmat[2 * idx], Ci = Cmat[2 * idx + 1];
        const float bcr = Br * Cr - Bi * Ci;
        const float bci = Br * Ci + Bi * Cr;
        const float e0r = 2.0f * (bcr * qr - bci * qi);
        const float e0i = 2.0f * (bcr * qi + bci * qr);
        // Ej = E0 * w^j
        const float e1r = e0r * wr - e0i * wi, e1i = e0r * wi + e0i * wr;
        const float e2r = e1r * wr - e1i * wi, e2i = e1r * wi + e1i * wr;
        const float e3r = e2r * wr - e2i * wi, e3i = e2r * wi + e2i * wr;
        const float b1 = er * er;                  // |w|^2
        p0[n] = make_float4(re * 1.44269504089f, im * 0.15915494309f,
                            2.0f * (wr * wr - wi * wi), b1 * b1);
        p1[n] = make_float4(e0r, e1r, e0i, e1i);
        p2[n] = make_float4(e2r, e3r, e2i, e3i);
    }
    __syncthreads();

    const int   l0  = half * HALF + tid * CHUNK;
    const float l0f = (float)l0;

    v2f acc2[CHUNK / 2];
#pragma unroll
    for (int k = 0; k < CHUNK / 2; ++k) acc2[k] = v2f{0.0f, 0.0f};

#pragma unroll 1
    for (int n = 0; n < NH; ++n) {
        const float4 P0 = p0[n];
        const float ax2 = P0.x * l0f;          // re*log2e*l0  (<= 0)
        if (ax2 < -43.3f) continue;            // 2^-43.3 ~ 1e-13: negligible
        const float4 Q1 = p1[n];
        const float4 Q2 = p2[n];
        float ph = P0.y * l0f;                 // phase in revolutions
        ph -= floorf(ph);
        const float s = __builtin_amdgcn_sinf(ph);   // sin(2*pi*ph)
        const float c = __builtin_amdgcn_cosf(ph);
        const float e = __builtin_amdgcn_exp2f(ax2); // e^{re*l0}
        const float kr = e * c;                // K(l0) = exp(dtA*l0)
        const float ki = e * s;
        // seeds: Pa = (u0,u1), Pb = (u2,u3);  u_j = Re(Ej * K)
        v2f Pa = v2f{Q1.x, Q1.y} * kr - v2f{Q1.z, Q1.w} * ki;
        v2f Pb = v2f{Q2.x, Q2.y} * kr - v2f{Q2.z, Q2.w} * ki;
        acc2[0] += Pa;
        acc2[1] += Pb;
        const v2f a2 = v2f{P0.z, P0.z};
        const v2f b2 = v2f{P0.w, P0.w};
#pragma unroll
        for (int k = 2; k < CHUNK / 2; ++k) {
            const v2f Pn = a2 * Pb - b2 * Pa;  // packed: pk_mul + pk_fma
            acc2[k] += Pn;
            Pa = Pb;
            Pb = Pn;
        }
    }

    float4* o = (float4*)(out + (size_t)h * LTOT + l0);
#pragma unroll
    for (int j = 0; j < CHUNK / 4; ++j)
        o[j] = make_float4(acc2[2 * j].x, acc2[2 * j].y,
                           acc2[2 * j + 1].x, acc2[2 * j + 1].y);
}

extern "C" void kernel_launch(void* const* d_in, const int* in_sizes, int n_in,
                              void* d_out, int out_size, void* d_ws, size_t ws_size,
                              hipStream_t stream)
{
    (void)in_sizes; (void)n_in; (void)d_ws; (void)ws_size; (void)out_size;
    const float* log_dt     = (const float*)d_in[0];
    const float* log_A_real = (const float*)d_in[1];
    const float* A_imag     = (const float*)d_in[2];
    const float* Bmat       = (const float*)d_in[3];
    const float* Cmat       = (const float*)d_in[4];
    float* out = (float*)d_out;

    s4_kernel<<<dim3(HDIM * (LTOT / HALF)), dim3(TPB), 0, stream>>>(
        log_dt, log_A_real, A_imag, Bmat, Cmat, out);
}